// Round 16
// baseline (183.178 us; speedup 1.0000x reference)
//
#include <hip/hip_runtime.h>

typedef _Float16 f16;
typedef f16    f16x2 __attribute__((ext_vector_type(2)));
typedef f16    f16x4 __attribute__((ext_vector_type(4)));
typedef f16    f16x8 __attribute__((ext_vector_type(8)));
typedef __fp16 fp16x2 __attribute__((ext_vector_type(2)));
typedef float  f32x4 __attribute__((ext_vector_type(4)));

#define NF 256      // features
#define NH 64       // hidden dim
#define NL 3        // hidden-to-hidden layers
#define NB 4        // 16-row batch tiles per wave -> 64 rows/wave
#define NWAVE 4
#define MT (NB * 16 * NWAVE)   // 256 rows per block
#define NTHR (NWAVE * 64)     // 256
#define WFRAG (NH * NH)

union U2  { f16x8 v8; f16x2 h[4]; };
union WB1 { f16x8 v8; fp16x2 p[4]; };   // {w01, w23, b01, b23}
union WO4 { f16x4 v4; fp16x2 p[2]; };

// sigma(p = 32ks + 8gr + j) = 32ks + 16*(j>>2) + 4gr + (j&3) baked into W
// staging: MFMA C-tile, packed pairwise, IS the next layer's B-fragment
// (verified r9-r15). h never touches LDS; zero barriers in the main kernel.
//
// r15 lesson: VALU diet didn't move the clock -> latency-bound at ~3.3
// waves/SIMD. Achieved occupancy tracks the __launch_bounds__ 2nd arg
// (r14: 5->5.1, r13/r15: 4->3.4). r15 state = 80 regs <= 512/5=102, so
// request 5 waves/EU — the single change this round.

__device__ __forceinline__ f16x2 pkmax(float a, float b) {
    fp16x2 p = __builtin_amdgcn_cvt_pkrtz(a, b);
    fp16x2 z = {(__fp16)0.f, (__fp16)0.f};
    p = __builtin_elementwise_max(p, z);
    return __builtin_bit_cast(f16x2, p);
}
__device__ __forceinline__ f16x2 pkfmarelu(fp16x2 x, fp16x2 w, fp16x2 b) {
    fp16x2 p = __builtin_elementwise_fma(x, w, b);   // v_pk_fma_f16
    fp16x2 z = {(__fp16)0.f, (__fp16)0.f};
    p = __builtin_elementwise_max(p, z);             // v_pk_max_f16
    return __builtin_bit_cast(f16x2, p);
}
__device__ __forceinline__ float dot2(f16x2 a, fp16x2 b, float c) {
#if __has_builtin(__builtin_amdgcn_fdot2)
    return __builtin_amdgcn_fdot2(__builtin_bit_cast(fp16x2, a), b, c, false);
#else
    return fmaf((float)a[0], (float)b[0], fmaf((float)a[1], (float)b[1], c));
#endif
}

// ---- prepass 1: Wh -> f16 RTN A-fragment plane with sigma baked into k ----
__global__ __launch_bounds__(256) void presplit_w(
    const float* __restrict__ Wh, f16* __restrict__ wsWh)
{
    __shared__ float wld[NH * NH];
    const int lf = blockIdx.x;            // l*NF + f
    const int t  = threadIdx.x;
    const float* __restrict__ src = Wh + (size_t)lf * WFRAG;
#pragma unroll
    for (int i = 0; i < 4; ++i)
        *(f32x4*)&wld[(i * 256 + t) * 4] = *(const f32x4*)&src[(i * 256 + t) * 4];
    __syncthreads();
#pragma unroll
    for (int g2 = 0; g2 < 2; ++g2) {
        const int g  = g2 * 256 + t;      // g = (mt*2+ks)*64 + ln
        const int ln = g & 63, ks = (g >> 6) & 1, mt = g >> 7;
        const int cl = ln & 15, gr = ln >> 4;
        const int m  = mt * 16 + cl;
        f16x8 hi;
#pragma unroll
        for (int jj = 0; jj < 8; ++jj) {
            const int u = 32 * ks + 16 * (jj >> 2) + 4 * gr + (jj & 3);  // sigma
            hi[jj] = (f16)wld[u * NH + m];   // RTN
        }
        *(f16x8*)&wsWh[((size_t)lf * 512 + g) * 8] = hi;
    }
}

// ---- prepass 2: pack W1/b1 (sigma-slot f16 pairs) and Wo (natural order) ----
__global__ __launch_bounds__(64) void prepack_small(
    const float* __restrict__ W1, const float* __restrict__ b1,
    const float* __restrict__ Wo,
    f16* __restrict__ wsW1B, f16* __restrict__ wsWo)
{
    const int f = blockIdx.x;
    const int t = threadIdx.x;
    if (t < 16) {
        // slot t = (ks*2+jq)*4 + gr -> units ub..ub+3
        const int gr = t & 3, jq = (t >> 2) & 1, ks = t >> 3;
        const int ub = 32 * ks + 16 * jq + 4 * gr;
        f16x8 o;
#pragma unroll
        for (int i = 0; i < 4; ++i) o[i]     = (f16)W1[f * NH + ub + i];
#pragma unroll
        for (int i = 0; i < 4; ++i) o[4 + i] = (f16)b1[f * NH + ub + i];
        *(f16x8*)&wsW1B[((size_t)f * 16 + t) * 8] = o;
    } else if (t < 32) {
        const int s = t - 16;             // s = mt*4 + gr
        const int mt = s >> 2, gr = s & 3;
        f16x4 o;
#pragma unroll
        for (int i = 0; i < 4; ++i)
            o[i] = (f16)Wo[f * NH + mt * 16 + gr * 4 + i];
        *(f16x4*)&wsWo[((size_t)f * 16 + s) * 4] = o;
    }
}

template <bool PRE>
__global__ __launch_bounds__(NTHR, 5) void permlp_v16(
    const float* __restrict__ x,
    const float* __restrict__ W1,
    const float* __restrict__ b1,
    const float* __restrict__ Wh,
    const float* __restrict__ bh,
    const float* __restrict__ Wo,
    const float* __restrict__ bo,
    const f16* __restrict__ wsWh,
    const f16* __restrict__ wsW1B,
    const f16* __restrict__ wsWo,
    float* __restrict__ out,
    int nby)
{
    // XCD-chunked bijective swizzle (nwg % 8 == 0): W working set L2-resident.
    const int nwg  = NF * nby;
    const int q    = nwg >> 3;
    const int bid  = blockIdx.x;
    const int wgid = (bid & 7) * q + (bid >> 3);
    const int f    = wgid / nby;
    const int by   = wgid - f * nby;

    const int tid = threadIdx.x;
    const int wv  = tid >> 6;
    const int ln  = tid & 63;
    const int cl  = ln & 15;
    const int gr  = ln >> 4;
    const int gb0 = by * MT + wv * (NB * 16);

    // W fragment loader (one 16x64 tile: 2 x f16x8 per lane)
    auto loadW = [&](const f16* __restrict__ baseH, const float* __restrict__ Wl,
                     int mt, f16x8 (&A)[2]) {
#pragma unroll
        for (int ks = 0; ks < 2; ++ks) {
            if constexpr (PRE) {
                A[ks] = *(const f16x8*)&baseH[(size_t)((mt * 2 + ks) * 64 + ln) * 8];
            } else {
                const int m = mt * 16 + cl;
                f16x8 hi8;
#pragma unroll
                for (int j = 0; j < 8; ++j) {
                    const int u = 32 * ks + 16 * (j >> 2) + 4 * gr + (j & 3);
                    hi8[j] = (f16)Wl[(size_t)u * NH + m];
                }
                A[ks] = hi8;
            }
        }
    };

    // ---- layer 1 straight into registers (sigma-ordered B-fragments) ----
    U2 HA[NB][2], HB[NB][2];
    {
        fp16x2 xx[NB];
#pragma unroll
        for (int bt = 0; bt < NB; ++bt) {
            const float xv = x[(size_t)(gb0 + bt * 16 + cl) * NF + f];
            xx[bt] = __builtin_amdgcn_cvt_pkrtz(xv, xv);
        }
        if constexpr (PRE) {
            const f16* __restrict__ wb1 = wsW1B + (size_t)f * 128;
#pragma unroll
            for (int ks = 0; ks < 2; ++ks)
#pragma unroll
                for (int jq = 0; jq < 2; ++jq) {
                    WB1 wb;
                    wb.v8 = *(const f16x8*)&wb1[(size_t)((ks * 2 + jq) * 4 + gr) * 8];
#pragma unroll
                    for (int bt = 0; bt < NB; ++bt) {
                        HA[bt][ks].h[jq * 2]     = pkfmarelu(xx[bt], wb.p[0], wb.p[2]);
                        HA[bt][ks].h[jq * 2 + 1] = pkfmarelu(xx[bt], wb.p[1], wb.p[3]);
                    }
                }
        } else {
            const float* __restrict__ w1 = W1 + f * NH;
            const float* __restrict__ bb = b1 + f * NH;
#pragma unroll
            for (int ks = 0; ks < 2; ++ks)
#pragma unroll
                for (int jq = 0; jq < 2; ++jq) {
                    const int ub = 32 * ks + 16 * jq + 4 * gr;
                    const f32x4 w4 = *(const f32x4*)&w1[ub];
                    const f32x4 b4 = *(const f32x4*)&bb[ub];
#pragma unroll
                    for (int bt = 0; bt < NB; ++bt) {
                        const float xv = (float)xx[bt][0];
                        HA[bt][ks].h[jq * 2]     = pkmax(fmaf(xv, w4[0], b4[0]), fmaf(xv, w4[1], b4[1]));
                        HA[bt][ks].h[jq * 2 + 1] = pkmax(fmaf(xv, w4[2], b4[2]), fmaf(xv, w4[3], b4[3]));
                    }
                }
        }
    }

    // ---- one hidden layer: I regs -> O regs, W double-buffered ----
    auto hidden = [&](U2 (&I)[NB][2], U2 (&O)[NB][2], const int l) {
        const f16* __restrict__ baseH = PRE ? wsWh + (size_t)(l * NF + f) * 4096 : nullptr;
        const float* __restrict__ Wl  = Wh + (size_t)(l * NF + f) * WFRAG;
        const float* __restrict__ bl  = bh + (size_t)(l * NF + f) * NH;
        f16x8 WA[2][2];   // [buf][ks]
        loadW(baseH, Wl, 0, WA[0]);
#pragma unroll
        for (int mt = 0; mt < 4; ++mt) {
            if (mt < 3)   // prefetch next tile while this tile computes
                loadW(baseH, Wl, mt + 1, WA[(mt + 1) & 1]);
            const f32x4 bias4 = *(const f32x4*)&bl[mt * 16 + gr * 4];
            f32x4 acc[NB];
#pragma unroll
            for (int bt = 0; bt < NB; ++bt) acc[bt] = bias4;
#pragma unroll
            for (int ks = 0; ks < 2; ++ks)
#pragma unroll
                for (int bt = 0; bt < NB; ++bt)
                    acc[bt] = __builtin_amdgcn_mfma_f32_16x16x32_f16(WA[mt & 1][ks], I[bt][ks].v8, acc[bt], 0, 0, 0);
            // C tile (batch=cl, units mt*16+gr*4+i) -> next-layer fragment
#pragma unroll
            for (int bt = 0; bt < NB; ++bt) {
                O[bt][mt >> 1].h[(mt & 1) * 2]     = pkmax(acc[bt][0], acc[bt][1]);
                O[bt][mt >> 1].h[(mt & 1) * 2 + 1] = pkmax(acc[bt][2], acc[bt][3]);
            }
        }
    };

    hidden(HA, HB, 0);
    hidden(HB, HA, 1);

    // ---- last hidden layer with fused output dot (reads HA) ----
    float souts[NB];
#pragma unroll
    for (int bt = 0; bt < NB; ++bt) souts[bt] = 0.f;
    {
        const int l = NL - 1;
        const f16* __restrict__ baseH = PRE ? wsWh + (size_t)(l * NF + f) * 4096 : nullptr;
        const float* __restrict__ Wl  = Wh + (size_t)(l * NF + f) * WFRAG;
        const float* __restrict__ bl  = bh + (size_t)(l * NF + f) * NH;
        f16x8 WA[2][2];
        loadW(baseH, Wl, 0, WA[0]);
#pragma unroll
        for (int mt = 0; mt < 4; ++mt) {
            if (mt < 3)
                loadW(baseH, Wl, mt + 1, WA[(mt + 1) & 1]);
            const f32x4 bias4 = *(const f32x4*)&bl[mt * 16 + gr * 4];
            f32x4 acc[NB];
#pragma unroll
            for (int bt = 0; bt < NB; ++bt) acc[bt] = bias4;
#pragma unroll
            for (int ks = 0; ks < 2; ++ks)
#pragma unroll
                for (int bt = 0; bt < NB; ++bt)
                    acc[bt] = __builtin_amdgcn_mfma_f32_16x16x32_f16(WA[mt & 1][ks], HA[bt][ks].v8, acc[bt], 0, 0, 0);
            if constexpr (PRE) {
                WO4 wo;
                wo.v4 = *(const f16x4*)&wsWo[((size_t)f * 16 + mt * 4 + gr) * 4];
#pragma unroll
                for (int bt = 0; bt < NB; ++bt) {
                    f16x2 p01 = pkmax(acc[bt][0], acc[bt][1]);   // relu'd h3 pairs
                    f16x2 p23 = pkmax(acc[bt][2], acc[bt][3]);
                    souts[bt] = dot2(p01, wo.p[0], souts[bt]);   // v_dot2_f32_f16
                    souts[bt] = dot2(p23, wo.p[1], souts[bt]);
                }
            } else {
                const f32x4 wov4 = *(const f32x4*)&Wo[f * NH + mt * 16 + gr * 4];
#pragma unroll
                for (int bt = 0; bt < NB; ++bt)
#pragma unroll
                    for (int i = 0; i < 4; ++i)
                        souts[bt] = fmaf(fmaxf(acc[bt][i], 0.f), wov4[i], souts[bt]);
            }
        }
    }

    // ---- commit: reduce over gr-groups, one atomic per row ----
    const float bof = bo[f];
#pragma unroll
    for (int bt = 0; bt < NB; ++bt) {
        float s = souts[bt];
        s += __shfl_xor(s, 16, 64);
        s += __shfl_xor(s, 32, 64);
        if (ln < 16)
            atomicAdd(&out[gb0 + bt * 16 + ln], s + bof);
    }
}

extern "C" void kernel_launch(void* const* d_in, const int* in_sizes, int n_in,
                              void* d_out, int out_size, void* d_ws, size_t ws_size,
                              hipStream_t stream)
{
    const float* x  = (const float*)d_in[0];
    const float* W1 = (const float*)d_in[1];
    const float* b1 = (const float*)d_in[2];
    const float* Wh = (const float*)d_in[3];
    const float* bh = (const float*)d_in[4];
    const float* Wo = (const float*)d_in[5];
    const float* bo = (const float*)d_in[6];
    float* out = (float*)d_out;

    const int B   = in_sizes[0] / NF;   // 16384
    const int nby = B / MT;             // 64

    hipMemsetAsync(out, 0, (size_t)out_size * sizeof(float), stream);

    const size_t whElems  = (size_t)NL * NF * WFRAG;   // 3.15M f16
    const size_t w1bElems = (size_t)NF * 16 * 8;       // 32K f16
    const size_t woElems  = (size_t)NF * 16 * 4;       // 16K f16
    const size_t needW    = (whElems + w1bElems + woElems) * sizeof(f16);
    dim3 grid(NF * nby);

    if (ws_size >= needW) {
        f16* wsWh  = (f16*)d_ws;
        f16* wsW1B = wsWh + whElems;
        f16* wsWo  = wsW1B + w1bElems;
        presplit_w<<<NL * NF, 256, 0, stream>>>(Wh, wsWh);
        prepack_small<<<NF, 64, 0, stream>>>(W1, b1, Wo, wsW1B, wsWo);
        permlp_v16<true><<<grid, dim3(NTHR), 0, stream>>>(
            x, W1, b1, Wh, bh, Wo, bo, wsWh, wsW1B, wsWo, out, nby);
    } else {
        permlp_v16<false><<<grid, dim3(NTHR), 0, stream>>>(
            x, W1, b1, Wh, bh, Wo, bo, nullptr, nullptr, nullptr, out, nby);
    }
}

// Round 17
// 142.560 us; speedup vs baseline: 1.2849x; 1.2849x over previous
//
#include <hip/hip_runtime.h>

typedef _Float16 f16;
typedef f16    f16x2 __attribute__((ext_vector_type(2)));
typedef f16    f16x4 __attribute__((ext_vector_type(4)));
typedef f16    f16x8 __attribute__((ext_vector_type(8)));
typedef __fp16 fp16x2 __attribute__((ext_vector_type(2)));
typedef float  f32x4 __attribute__((ext_vector_type(4)));

#define NF 256      // features
#define NH 64       // hidden dim
#define NL 3        // hidden-to-hidden layers
#define NB 4        // 16-row batch tiles per wave -> 64 rows/wave
#define NWAVE 4
#define MT (NB * 16 * NWAVE)   // 256 rows per block
#define NTHR (NWAVE * 64)     // 256
#define WFRAG (NH * NH)

union U2  { f16x8 v8; f16x2 h[4]; };
union WB1 { f16x8 v8; fp16x2 p[4]; };   // {w01, w23, b01, b23}
union WO4 { f16x4 v4; fp16x2 p[2]; };

// sigma(p = 32ks + 8gr + j) = 32ks + 16*(j>>2) + 4gr + (j&3) baked into W
// staging: MFMA C-tile, packed pairwise, IS the next layer's B-fragment
// (verified r9-r16). h never touches LDS; zero barriers in the main kernel.
//
// Occupancy note (r12/r14/r16 evidence): HW register allocation is
// quantized (64/128/256) -> this kernel's ~80 live regs round to 128 =
// 4 waves/SIMD, and requesting more FORCES spill. Stay at 4; use the
// ~48-reg slack for deeper prefetch instead:
//  - first W tile issued BEFORE layer-1 VALU (hides L2 latency)
//  - cross-layer W prefetch at mt==3 (kills 3 layer-boundary stalls)
//  - tail Wo fragments hoisted at tail entry
//  - setprio(1) around MFMA clusters (barrier-free staggered waves =
//    the attn-like regime where T5 measured +4-7%)

__device__ __forceinline__ f16x2 pkmax(float a, float b) {
    fp16x2 p = __builtin_amdgcn_cvt_pkrtz(a, b);
    fp16x2 z = {(__fp16)0.f, (__fp16)0.f};
    p = __builtin_elementwise_max(p, z);
    return __builtin_bit_cast(f16x2, p);
}
__device__ __forceinline__ f16x2 pkfmarelu(fp16x2 x, fp16x2 w, fp16x2 b) {
    fp16x2 p = __builtin_elementwise_fma(x, w, b);   // v_pk_fma_f16
    fp16x2 z = {(__fp16)0.f, (__fp16)0.f};
    p = __builtin_elementwise_max(p, z);             // v_pk_max_f16
    return __builtin_bit_cast(f16x2, p);
}
__device__ __forceinline__ float dot2(f16x2 a, fp16x2 b, float c) {
#if __has_builtin(__builtin_amdgcn_fdot2)
    return __builtin_amdgcn_fdot2(__builtin_bit_cast(fp16x2, a), b, c, false);
#else
    return fmaf((float)a[0], (float)b[0], fmaf((float)a[1], (float)b[1], c));
#endif
}

// ---- prepass 1: Wh -> f16 RTN A-fragment plane with sigma baked into k ----
__global__ __launch_bounds__(256) void presplit_w(
    const float* __restrict__ Wh, f16* __restrict__ wsWh)
{
    __shared__ float wld[NH * NH];
    const int lf = blockIdx.x;            // l*NF + f
    const int t  = threadIdx.x;
    const float* __restrict__ src = Wh + (size_t)lf * WFRAG;
#pragma unroll
    for (int i = 0; i < 4; ++i)
        *(f32x4*)&wld[(i * 256 + t) * 4] = *(const f32x4*)&src[(i * 256 + t) * 4];
    __syncthreads();
#pragma unroll
    for (int g2 = 0; g2 < 2; ++g2) {
        const int g  = g2 * 256 + t;      // g = (mt*2+ks)*64 + ln
        const int ln = g & 63, ks = (g >> 6) & 1, mt = g >> 7;
        const int cl = ln & 15, gr = ln >> 4;
        const int m  = mt * 16 + cl;
        f16x8 hi;
#pragma unroll
        for (int jj = 0; jj < 8; ++jj) {
            const int u = 32 * ks + 16 * (jj >> 2) + 4 * gr + (jj & 3);  // sigma
            hi[jj] = (f16)wld[u * NH + m];   // RTN
        }
        *(f16x8*)&wsWh[((size_t)lf * 512 + g) * 8] = hi;
    }
}

// ---- prepass 2: pack W1/b1 (sigma-slot f16 pairs) and Wo (natural order) ----
__global__ __launch_bounds__(64) void prepack_small(
    const float* __restrict__ W1, const float* __restrict__ b1,
    const float* __restrict__ Wo,
    f16* __restrict__ wsW1B, f16* __restrict__ wsWo)
{
    const int f = blockIdx.x;
    const int t = threadIdx.x;
    if (t < 16) {
        // slot t = (ks*2+jq)*4 + gr -> units ub..ub+3
        const int gr = t & 3, jq = (t >> 2) & 1, ks = t >> 3;
        const int ub = 32 * ks + 16 * jq + 4 * gr;
        f16x8 o;
#pragma unroll
        for (int i = 0; i < 4; ++i) o[i]     = (f16)W1[f * NH + ub + i];
#pragma unroll
        for (int i = 0; i < 4; ++i) o[4 + i] = (f16)b1[f * NH + ub + i];
        *(f16x8*)&wsW1B[((size_t)f * 16 + t) * 8] = o;
    } else if (t < 32) {
        const int s = t - 16;             // s = mt*4 + gr
        const int mt = s >> 2, gr = s & 3;
        f16x4 o;
#pragma unroll
        for (int i = 0; i < 4; ++i)
            o[i] = (f16)Wo[f * NH + mt * 16 + gr * 4 + i];
        *(f16x4*)&wsWo[((size_t)f * 16 + s) * 4] = o;
    }
}

template <bool PRE>
__global__ __launch_bounds__(NTHR, 4) void permlp_v17(
    const float* __restrict__ x,
    const float* __restrict__ W1,
    const float* __restrict__ b1,
    const float* __restrict__ Wh,
    const float* __restrict__ bh,
    const float* __restrict__ Wo,
    const float* __restrict__ bo,
    const f16* __restrict__ wsWh,
    const f16* __restrict__ wsW1B,
    const f16* __restrict__ wsWo,
    float* __restrict__ out,
    int nby)
{
    // XCD-chunked bijective swizzle (nwg % 8 == 0): W working set L2-resident.
    const int nwg  = NF * nby;
    const int q    = nwg >> 3;
    const int bid  = blockIdx.x;
    const int wgid = (bid & 7) * q + (bid >> 3);
    const int f    = wgid / nby;
    const int by   = wgid - f * nby;

    const int tid = threadIdx.x;
    const int wv  = tid >> 6;
    const int ln  = tid & 63;
    const int cl  = ln & 15;
    const int gr  = ln >> 4;
    const int gb0 = by * MT + wv * (NB * 16);

    // W fragment loader (one 16x64 tile: 2 x f16x8 per lane)
    auto loadW = [&](int l, int mt, f16x8 (&A)[2]) {
#pragma unroll
        for (int ks = 0; ks < 2; ++ks) {
            if constexpr (PRE) {
                const f16* __restrict__ baseH = wsWh + (size_t)(l * NF + f) * 4096;
                A[ks] = *(const f16x8*)&baseH[(size_t)((mt * 2 + ks) * 64 + ln) * 8];
            } else {
                const float* __restrict__ Wl = Wh + (size_t)(l * NF + f) * WFRAG;
                const int m = mt * 16 + cl;
                f16x8 hi8;
#pragma unroll
                for (int j = 0; j < 8; ++j) {
                    const int u = 32 * ks + 16 * (j >> 2) + 4 * gr + (j & 3);
                    hi8[j] = (f16)Wl[(size_t)u * NH + m];
                }
                A[ks] = hi8;
            }
        }
    };

    // issue layer-0's first W tile NOW: layer-1's VALU below hides the L2 hit
    f16x8 WA[2][2];   // [buf][ks], shared across all layers
    loadW(0, 0, WA[0]);

    // ---- layer 1 straight into registers (sigma-ordered B-fragments) ----
    U2 HA[NB][2], HB[NB][2];
    {
        fp16x2 xx[NB];
#pragma unroll
        for (int bt = 0; bt < NB; ++bt) {
            const float xv = x[(size_t)(gb0 + bt * 16 + cl) * NF + f];
            xx[bt] = __builtin_amdgcn_cvt_pkrtz(xv, xv);
        }
        if constexpr (PRE) {
            const f16* __restrict__ wb1 = wsW1B + (size_t)f * 128;
#pragma unroll
            for (int ks = 0; ks < 2; ++ks)
#pragma unroll
                for (int jq = 0; jq < 2; ++jq) {
                    WB1 wb;
                    wb.v8 = *(const f16x8*)&wb1[(size_t)((ks * 2 + jq) * 4 + gr) * 8];
#pragma unroll
                    for (int bt = 0; bt < NB; ++bt) {
                        HA[bt][ks].h[jq * 2]     = pkfmarelu(xx[bt], wb.p[0], wb.p[2]);
                        HA[bt][ks].h[jq * 2 + 1] = pkfmarelu(xx[bt], wb.p[1], wb.p[3]);
                    }
                }
        } else {
            const float* __restrict__ w1 = W1 + f * NH;
            const float* __restrict__ bb = b1 + f * NH;
#pragma unroll
            for (int ks = 0; ks < 2; ++ks)
#pragma unroll
                for (int jq = 0; jq < 2; ++jq) {
                    const int ub = 32 * ks + 16 * jq + 4 * gr;
                    const f32x4 w4 = *(const f32x4*)&w1[ub];
                    const f32x4 b4 = *(const f32x4*)&bb[ub];
#pragma unroll
                    for (int bt = 0; bt < NB; ++bt) {
                        const float xv = (float)xx[bt][0];
                        HA[bt][ks].h[jq * 2]     = pkmax(fmaf(xv, w4[0], b4[0]), fmaf(xv, w4[1], b4[1]));
                        HA[bt][ks].h[jq * 2 + 1] = pkmax(fmaf(xv, w4[2], b4[2]), fmaf(xv, w4[3], b4[3]));
                    }
                }
        }
    }

    // ---- one hidden layer: I regs -> O regs; W dbuf with cross-layer
    // ---- prefetch (mt==3 loads NEXT layer's tile 0 into WA[0]) ----
    auto hidden = [&](U2 (&I)[NB][2], U2 (&O)[NB][2], const int l) {
        const float* __restrict__ bl = bh + (size_t)(l * NF + f) * NH;
#pragma unroll
        for (int mt = 0; mt < 4; ++mt) {
            if (mt < 3)
                loadW(l, mt + 1, WA[(mt + 1) & 1]);
            else
                loadW(l + 1, 0, WA[0]);   // cross-layer prefetch (parity: 3&1=1 in use)
            const f32x4 bias4 = *(const f32x4*)&bl[mt * 16 + gr * 4];
            f32x4 acc[NB];
#pragma unroll
            for (int bt = 0; bt < NB; ++bt) acc[bt] = bias4;
            __builtin_amdgcn_s_setprio(1);
#pragma unroll
            for (int ks = 0; ks < 2; ++ks)
#pragma unroll
                for (int bt = 0; bt < NB; ++bt)
                    acc[bt] = __builtin_amdgcn_mfma_f32_16x16x32_f16(WA[mt & 1][ks], I[bt][ks].v8, acc[bt], 0, 0, 0);
            __builtin_amdgcn_s_setprio(0);
            // C tile (batch=cl, units mt*16+gr*4+i) -> next-layer fragment
#pragma unroll
            for (int bt = 0; bt < NB; ++bt) {
                O[bt][mt >> 1].h[(mt & 1) * 2]     = pkmax(acc[bt][0], acc[bt][1]);
                O[bt][mt >> 1].h[(mt & 1) * 2 + 1] = pkmax(acc[bt][2], acc[bt][3]);
            }
        }
    };

    hidden(HA, HB, 0);   // prefetches W(1,0) at its mt==3
    hidden(HB, HA, 1);   // prefetches W(2,0) at its mt==3

    // ---- last hidden layer with fused output dot (reads HA; WA[0] ready) ----
    float souts[NB];
#pragma unroll
    for (int bt = 0; bt < NB; ++bt) souts[bt] = 0.f;
    {
        const int l = NL - 1;
        const float* __restrict__ bl = bh + (size_t)(l * NF + f) * NH;
        // hoist all 4 Wo fragments up front (PRE path)
        WO4 wo[4];
        if constexpr (PRE) {
#pragma unroll
            for (int mt = 0; mt < 4; ++mt)
                wo[mt].v4 = *(const f16x4*)&wsWo[((size_t)f * 16 + mt * 4 + gr) * 4];
        }
#pragma unroll
        for (int mt = 0; mt < 4; ++mt) {
            if (mt < 3)
                loadW(l, mt + 1, WA[(mt + 1) & 1]);
            const f32x4 bias4 = *(const f32x4*)&bl[mt * 16 + gr * 4];
            f32x4 acc[NB];
#pragma unroll
            for (int bt = 0; bt < NB; ++bt) acc[bt] = bias4;
            __builtin_amdgcn_s_setprio(1);
#pragma unroll
            for (int ks = 0; ks < 2; ++ks)
#pragma unroll
                for (int bt = 0; bt < NB; ++bt)
                    acc[bt] = __builtin_amdgcn_mfma_f32_16x16x32_f16(WA[mt & 1][ks], HA[bt][ks].v8, acc[bt], 0, 0, 0);
            __builtin_amdgcn_s_setprio(0);
            if constexpr (PRE) {
#pragma unroll
                for (int bt = 0; bt < NB; ++bt) {
                    f16x2 p01 = pkmax(acc[bt][0], acc[bt][1]);   // relu'd h3 pairs
                    f16x2 p23 = pkmax(acc[bt][2], acc[bt][3]);
                    souts[bt] = dot2(p01, wo[mt].p[0], souts[bt]);   // v_dot2_f32_f16
                    souts[bt] = dot2(p23, wo[mt].p[1], souts[bt]);
                }
            } else {
                const f32x4 wov4 = *(const f32x4*)&Wo[f * NH + mt * 16 + gr * 4];
#pragma unroll
                for (int bt = 0; bt < NB; ++bt)
#pragma unroll
                    for (int i = 0; i < 4; ++i)
                        souts[bt] = fmaf(fmaxf(acc[bt][i], 0.f), wov4[i], souts[bt]);
            }
        }
    }

    // ---- commit: reduce over gr-groups, one atomic per row ----
    const float bof = bo[f];
#pragma unroll
    for (int bt = 0; bt < NB; ++bt) {
        float s = souts[bt];
        s += __shfl_xor(s, 16, 64);
        s += __shfl_xor(s, 32, 64);
        if (ln < 16)
            atomicAdd(&out[gb0 + bt * 16 + ln], s + bof);
    }
}

extern "C" void kernel_launch(void* const* d_in, const int* in_sizes, int n_in,
                              void* d_out, int out_size, void* d_ws, size_t ws_size,
                              hipStream_t stream)
{
    const float* x  = (const float*)d_in[0];
    const float* W1 = (const float*)d_in[1];
    const float* b1 = (const float*)d_in[2];
    const float* Wh = (const float*)d_in[3];
    const float* bh = (const float*)d_in[4];
    const float* Wo = (const float*)d_in[5];
    const float* bo = (const float*)d_in[6];
    float* out = (float*)d_out;

    const int B   = in_sizes[0] / NF;   // 16384
    const int nby = B / MT;             // 64

    hipMemsetAsync(out, 0, (size_t)out_size * sizeof(float), stream);

    const size_t whElems  = (size_t)NL * NF * WFRAG;   // 3.15M f16
    const size_t w1bElems = (size_t)NF * 16 * 8;       // 32K f16
    const size_t woElems  = (size_t)NF * 16 * 4;       // 16K f16
    const size_t needW    = (whElems + w1bElems + woElems) * sizeof(f16);
    dim3 grid(NF * nby);

    if (ws_size >= needW) {
        f16* wsWh  = (f16*)d_ws;
        f16* wsW1B = wsWh + whElems;
        f16* wsWo  = wsW1B + w1bElems;
        presplit_w<<<NL * NF, 256, 0, stream>>>(Wh, wsWh);
        prepack_small<<<NF, 64, 0, stream>>>(W1, b1, Wo, wsW1B, wsWo);
        permlp_v17<true><<<grid, dim3(NTHR), 0, stream>>>(
            x, W1, b1, Wh, bh, Wo, bo, wsWh, wsW1B, wsWo, out, nby);
    } else {
        permlp_v17<false><<<grid, dim3(NTHR), 0, stream>>>(
            x, W1, b1, Wh, bh, Wo, bo, nullptr, nullptr, nullptr, out, nby);
    }
}

// Round 18
// 133.451 us; speedup vs baseline: 1.3726x; 1.0683x over previous
//
#include <hip/hip_runtime.h>

typedef _Float16 f16;
typedef f16    f16x2 __attribute__((ext_vector_type(2)));
typedef f16    f16x4 __attribute__((ext_vector_type(4)));
typedef f16    f16x8 __attribute__((ext_vector_type(8)));
typedef __fp16 fp16x2 __attribute__((ext_vector_type(2)));
typedef float  f32x4 __attribute__((ext_vector_type(4)));

#define NF 256      // features
#define NH 64       // hidden dim
#define NL 3        // hidden-to-hidden layers
#define NB 4        // 16-row batch tiles per wave -> 64 rows/wave
#define NWAVE 4
#define MT (NB * 16 * NWAVE)   // 256 rows per block
#define NTHR (NWAVE * 64)     // 256
#define WFRAG (NH * NH)

union U2  { f16x8 v8; f16x2 h[4]; };
union WB1 { f16x8 v8; fp16x2 p[4]; };   // {w01, w23, b01, b23}
union WO4 { f16x4 v4; fp16x2 p[2]; };

// sigma(p = 32ks + 8gr + j) = 32ks + 16*(j>>2) + 4gr + (j&3) baked into W
// staging: MFMA C-tile, packed pairwise, IS the next layer's B-fragment
// (verified r9-r17). h never touches LDS; zero barriers in the main kernel.
//
// This is r15 (best measured: 133.6 us) + tail Wo hoist only.
// Ruled out by measurement: >4 waves/SIMD (reg quantum 64/128/256 ->
// spill, r12/r16), setprio + cross-layer prefetch bundle (r17, -9 us),
// NB=3 occupancy trade (r14), 2-/3-term splits (r10/r11 superseded by
// verified 1-term absmax 0.0039 vs threshold 0.021).

__device__ __forceinline__ f16x2 pkmax(float a, float b) {
    fp16x2 p = __builtin_amdgcn_cvt_pkrtz(a, b);
    fp16x2 z = {(__fp16)0.f, (__fp16)0.f};
    p = __builtin_elementwise_max(p, z);
    return __builtin_bit_cast(f16x2, p);
}
__device__ __forceinline__ f16x2 pkfmarelu(fp16x2 x, fp16x2 w, fp16x2 b) {
    fp16x2 p = __builtin_elementwise_fma(x, w, b);   // v_pk_fma_f16
    fp16x2 z = {(__fp16)0.f, (__fp16)0.f};
    p = __builtin_elementwise_max(p, z);             // v_pk_max_f16
    return __builtin_bit_cast(f16x2, p);
}
__device__ __forceinline__ float dot2(f16x2 a, fp16x2 b, float c) {
#if __has_builtin(__builtin_amdgcn_fdot2)
    return __builtin_amdgcn_fdot2(__builtin_bit_cast(fp16x2, a), b, c, false);
#else
    return fmaf((float)a[0], (float)b[0], fmaf((float)a[1], (float)b[1], c));
#endif
}

// ---- prepass 1: Wh -> f16 RTN A-fragment plane with sigma baked into k ----
__global__ __launch_bounds__(256) void presplit_w(
    const float* __restrict__ Wh, f16* __restrict__ wsWh)
{
    __shared__ float wld[NH * NH];
    const int lf = blockIdx.x;            // l*NF + f
    const int t  = threadIdx.x;
    const float* __restrict__ src = Wh + (size_t)lf * WFRAG;
#pragma unroll
    for (int i = 0; i < 4; ++i)
        *(f32x4*)&wld[(i * 256 + t) * 4] = *(const f32x4*)&src[(i * 256 + t) * 4];
    __syncthreads();
#pragma unroll
    for (int g2 = 0; g2 < 2; ++g2) {
        const int g  = g2 * 256 + t;      // g = (mt*2+ks)*64 + ln
        const int ln = g & 63, ks = (g >> 6) & 1, mt = g >> 7;
        const int cl = ln & 15, gr = ln >> 4;
        const int m  = mt * 16 + cl;
        f16x8 hi;
#pragma unroll
        for (int jj = 0; jj < 8; ++jj) {
            const int u = 32 * ks + 16 * (jj >> 2) + 4 * gr + (jj & 3);  // sigma
            hi[jj] = (f16)wld[u * NH + m];   // RTN
        }
        *(f16x8*)&wsWh[((size_t)lf * 512 + g) * 8] = hi;
    }
}

// ---- prepass 2: pack W1/b1 (sigma-slot f16 pairs) and Wo (natural order) ----
__global__ __launch_bounds__(64) void prepack_small(
    const float* __restrict__ W1, const float* __restrict__ b1,
    const float* __restrict__ Wo,
    f16* __restrict__ wsW1B, f16* __restrict__ wsWo)
{
    const int f = blockIdx.x;
    const int t = threadIdx.x;
    if (t < 16) {
        // slot t = (ks*2+jq)*4 + gr -> units ub..ub+3
        const int gr = t & 3, jq = (t >> 2) & 1, ks = t >> 3;
        const int ub = 32 * ks + 16 * jq + 4 * gr;
        f16x8 o;
#pragma unroll
        for (int i = 0; i < 4; ++i) o[i]     = (f16)W1[f * NH + ub + i];
#pragma unroll
        for (int i = 0; i < 4; ++i) o[4 + i] = (f16)b1[f * NH + ub + i];
        *(f16x8*)&wsW1B[((size_t)f * 16 + t) * 8] = o;
    } else if (t < 32) {
        const int s = t - 16;             // s = mt*4 + gr
        const int mt = s >> 2, gr = s & 3;
        f16x4 o;
#pragma unroll
        for (int i = 0; i < 4; ++i)
            o[i] = (f16)Wo[f * NH + mt * 16 + gr * 4 + i];
        *(f16x4*)&wsWo[((size_t)f * 16 + s) * 4] = o;
    }
}

template <bool PRE>
__global__ __launch_bounds__(NTHR, 4) void permlp_v18(
    const float* __restrict__ x,
    const float* __restrict__ W1,
    const float* __restrict__ b1,
    const float* __restrict__ Wh,
    const float* __restrict__ bh,
    const float* __restrict__ Wo,
    const float* __restrict__ bo,
    const f16* __restrict__ wsWh,
    const f16* __restrict__ wsW1B,
    const f16* __restrict__ wsWo,
    float* __restrict__ out,
    int nby)
{
    // XCD-chunked bijective swizzle (nwg % 8 == 0): W working set L2-resident.
    const int nwg  = NF * nby;
    const int q    = nwg >> 3;
    const int bid  = blockIdx.x;
    const int wgid = (bid & 7) * q + (bid >> 3);
    const int f    = wgid / nby;
    const int by   = wgid - f * nby;

    const int tid = threadIdx.x;
    const int wv  = tid >> 6;
    const int ln  = tid & 63;
    const int cl  = ln & 15;
    const int gr  = ln >> 4;
    const int gb0 = by * MT + wv * (NB * 16);

    // W fragment loader (one 16x64 tile: 2 x f16x8 per lane)
    auto loadW = [&](const f16* __restrict__ baseH, const float* __restrict__ Wl,
                     int mt, f16x8 (&A)[2]) {
#pragma unroll
        for (int ks = 0; ks < 2; ++ks) {
            if constexpr (PRE) {
                A[ks] = *(const f16x8*)&baseH[(size_t)((mt * 2 + ks) * 64 + ln) * 8];
            } else {
                const int m = mt * 16 + cl;
                f16x8 hi8;
#pragma unroll
                for (int j = 0; j < 8; ++j) {
                    const int u = 32 * ks + 16 * (j >> 2) + 4 * gr + (j & 3);
                    hi8[j] = (f16)Wl[(size_t)u * NH + m];
                }
                A[ks] = hi8;
            }
        }
    };

    // ---- layer 1 straight into registers (sigma-ordered B-fragments) ----
    U2 HA[NB][2], HB[NB][2];
    {
        fp16x2 xx[NB];
#pragma unroll
        for (int bt = 0; bt < NB; ++bt) {
            const float xv = x[(size_t)(gb0 + bt * 16 + cl) * NF + f];
            xx[bt] = __builtin_amdgcn_cvt_pkrtz(xv, xv);
        }
        if constexpr (PRE) {
            const f16* __restrict__ wb1 = wsW1B + (size_t)f * 128;
#pragma unroll
            for (int ks = 0; ks < 2; ++ks)
#pragma unroll
                for (int jq = 0; jq < 2; ++jq) {
                    WB1 wb;
                    wb.v8 = *(const f16x8*)&wb1[(size_t)((ks * 2 + jq) * 4 + gr) * 8];
#pragma unroll
                    for (int bt = 0; bt < NB; ++bt) {
                        HA[bt][ks].h[jq * 2]     = pkfmarelu(xx[bt], wb.p[0], wb.p[2]);
                        HA[bt][ks].h[jq * 2 + 1] = pkfmarelu(xx[bt], wb.p[1], wb.p[3]);
                    }
                }
        } else {
            const float* __restrict__ w1 = W1 + f * NH;
            const float* __restrict__ bb = b1 + f * NH;
#pragma unroll
            for (int ks = 0; ks < 2; ++ks)
#pragma unroll
                for (int jq = 0; jq < 2; ++jq) {
                    const int ub = 32 * ks + 16 * jq + 4 * gr;
                    const f32x4 w4 = *(const f32x4*)&w1[ub];
                    const f32x4 b4 = *(const f32x4*)&bb[ub];
#pragma unroll
                    for (int bt = 0; bt < NB; ++bt) {
                        const float xv = (float)xx[bt][0];
                        HA[bt][ks].h[jq * 2]     = pkmax(fmaf(xv, w4[0], b4[0]), fmaf(xv, w4[1], b4[1]));
                        HA[bt][ks].h[jq * 2 + 1] = pkmax(fmaf(xv, w4[2], b4[2]), fmaf(xv, w4[3], b4[3]));
                    }
                }
        }
    }

    // ---- one hidden layer: I regs -> O regs, W double-buffered ----
    auto hidden = [&](U2 (&I)[NB][2], U2 (&O)[NB][2], const int l) {
        const f16* __restrict__ baseH = PRE ? wsWh + (size_t)(l * NF + f) * 4096 : nullptr;
        const float* __restrict__ Wl  = Wh + (size_t)(l * NF + f) * WFRAG;
        const float* __restrict__ bl  = bh + (size_t)(l * NF + f) * NH;
        f16x8 WA[2][2];   // [buf][ks]
        loadW(baseH, Wl, 0, WA[0]);
#pragma unroll
        for (int mt = 0; mt < 4; ++mt) {
            if (mt < 3)   // prefetch next tile while this tile computes
                loadW(baseH, Wl, mt + 1, WA[(mt + 1) & 1]);
            const f32x4 bias4 = *(const f32x4*)&bl[mt * 16 + gr * 4];
            f32x4 acc[NB];
#pragma unroll
            for (int bt = 0; bt < NB; ++bt) acc[bt] = bias4;
#pragma unroll
            for (int ks = 0; ks < 2; ++ks)
#pragma unroll
                for (int bt = 0; bt < NB; ++bt)
                    acc[bt] = __builtin_amdgcn_mfma_f32_16x16x32_f16(WA[mt & 1][ks], I[bt][ks].v8, acc[bt], 0, 0, 0);
            // C tile (batch=cl, units mt*16+gr*4+i) -> next-layer fragment
#pragma unroll
            for (int bt = 0; bt < NB; ++bt) {
                O[bt][mt >> 1].h[(mt & 1) * 2]     = pkmax(acc[bt][0], acc[bt][1]);
                O[bt][mt >> 1].h[(mt & 1) * 2 + 1] = pkmax(acc[bt][2], acc[bt][3]);
            }
        }
    };

    hidden(HA, HB, 0);
    hidden(HB, HA, 1);

    // ---- last hidden layer with fused output dot (reads HA) ----
    float souts[NB];
#pragma unroll
    for (int bt = 0; bt < NB; ++bt) souts[bt] = 0.f;
    {
        const int l = NL - 1;
        const f16* __restrict__ baseH = PRE ? wsWh + (size_t)(l * NF + f) * 4096 : nullptr;
        const float* __restrict__ Wl  = Wh + (size_t)(l * NF + f) * WFRAG;
        const float* __restrict__ bl  = bh + (size_t)(l * NF + f) * NH;
        // hoist all 4 Wo fragments at tail entry (outside the mt loop)
        WO4 wo[4];
        if constexpr (PRE) {
#pragma unroll
            for (int mt = 0; mt < 4; ++mt)
                wo[mt].v4 = *(const f16x4*)&wsWo[((size_t)f * 16 + mt * 4 + gr) * 4];
        }
        f16x8 WA[2][2];
        loadW(baseH, Wl, 0, WA[0]);
#pragma unroll
        for (int mt = 0; mt < 4; ++mt) {
            if (mt < 3)
                loadW(baseH, Wl, mt + 1, WA[(mt + 1) & 1]);
            const f32x4 bias4 = *(const f32x4*)&bl[mt * 16 + gr * 4];
            f32x4 acc[NB];
#pragma unroll
            for (int bt = 0; bt < NB; ++bt) acc[bt] = bias4;
#pragma unroll
            for (int ks = 0; ks < 2; ++ks)
#pragma unroll
                for (int bt = 0; bt < NB; ++bt)
                    acc[bt] = __builtin_amdgcn_mfma_f32_16x16x32_f16(WA[mt & 1][ks], HA[bt][ks].v8, acc[bt], 0, 0, 0);
            if constexpr (PRE) {
#pragma unroll
                for (int bt = 0; bt < NB; ++bt) {
                    f16x2 p01 = pkmax(acc[bt][0], acc[bt][1]);   // relu'd h3 pairs
                    f16x2 p23 = pkmax(acc[bt][2], acc[bt][3]);
                    souts[bt] = dot2(p01, wo[mt].p[0], souts[bt]);   // v_dot2_f32_f16
                    souts[bt] = dot2(p23, wo[mt].p[1], souts[bt]);
                }
            } else {
                const f32x4 wov4 = *(const f32x4*)&Wo[f * NH + mt * 16 + gr * 4];
#pragma unroll
                for (int bt = 0; bt < NB; ++bt)
#pragma unroll
                    for (int i = 0; i < 4; ++i)
                        souts[bt] = fmaf(fmaxf(acc[bt][i], 0.f), wov4[i], souts[bt]);
            }
        }
    }

    // ---- commit: reduce over gr-groups, one atomic per row ----
    const float bof = bo[f];
#pragma unroll
    for (int bt = 0; bt < NB; ++bt) {
        float s = souts[bt];
        s += __shfl_xor(s, 16, 64);
        s += __shfl_xor(s, 32, 64);
        if (ln < 16)
            atomicAdd(&out[gb0 + bt * 16 + ln], s + bof);
    }
}

extern "C" void kernel_launch(void* const* d_in, const int* in_sizes, int n_in,
                              void* d_out, int out_size, void* d_ws, size_t ws_size,
                              hipStream_t stream)
{
    const float* x  = (const float*)d_in[0];
    const float* W1 = (const float*)d_in[1];
    const float* b1 = (const float*)d_in[2];
    const float* Wh = (const float*)d_in[3];
    const float* bh = (const float*)d_in[4];
    const float* Wo = (const float*)d_in[5];
    const float* bo = (const float*)d_in[6];
    float* out = (float*)d_out;

    const int B   = in_sizes[0] / NF;   // 16384
    const int nby = B / MT;             // 64

    hipMemsetAsync(out, 0, (size_t)out_size * sizeof(float), stream);

    const size_t whElems  = (size_t)NL * NF * WFRAG;   // 3.15M f16
    const size_t w1bElems = (size_t)NF * 16 * 8;       // 32K f16
    const size_t woElems  = (size_t)NF * 16 * 4;       // 16K f16
    const size_t needW    = (whElems + w1bElems + woElems) * sizeof(f16);
    dim3 grid(NF * nby);

    if (ws_size >= needW) {
        f16* wsWh  = (f16*)d_ws;
        f16* wsW1B = wsWh + whElems;
        f16* wsWo  = wsW1B + w1bElems;
        presplit_w<<<NL * NF, 256, 0, stream>>>(Wh, wsWh);
        prepack_small<<<NF, 64, 0, stream>>>(W1, b1, Wo, wsW1B, wsWo);
        permlp_v18<true><<<grid, dim3(NTHR), 0, stream>>>(
            x, W1, b1, Wh, bh, Wo, bo, wsWh, wsW1B, wsWo, out, nby);
    } else {
        permlp_v18<false><<<grid, dim3(NTHR), 0, stream>>>(
            x, W1, b1, Wh, bh, Wo, bo, nullptr, nullptr, nullptr, out, nby);
    }
}